// Round 1
// baseline (174.183 us; speedup 1.0000x reference)
//
#include <hip/hip_runtime.h>
#include <math.h>

#define N_CUR 128
#define N_PREV 160
#define K_RECT (N_CUR + N_CUR + N_PREV)   // 416 rectangles
#define HS 1080                            // subsampled height
#define WS 1920                            // subsampled width
#define W_FULL 3840
#define TILE_W 32
#define TILE_H 8

// ---------------------------------------------------------------------------
// Kernel 1: matching logic -> rectangle list (box as float4 [x1,y1,x2,y2), val)
// Inactive rects are emitted as empty boxes (all zero) so the painter can
// skip them via the geometric cull alone.
// ---------------------------------------------------------------------------
__global__ __launch_bounds__(256) void prep_rects(
    const float* __restrict__ boxes,        // [N,4]
    const float* __restrict__ scores,       // [N]
    const float* __restrict__ flags,        // [N]
    const float* __restrict__ boxes_prev,   // [M,4]
    const float* __restrict__ scores_prev,  // [M]
    const float* __restrict__ flags_prev,   // [M]
    const int*   __restrict__ ids,          // [N]
    const int*   __restrict__ ids_prev,     // [M]
    float4* __restrict__ rbox,              // [K_RECT]
    float*  __restrict__ rval)              // [K_RECT]
{
    __shared__ float4 sbp[N_PREV];      // floored/2 prev boxes
    __shared__ float  sareap[N_PREV];
    __shared__ int    sidp[N_PREV];
    __shared__ int    smatched[N_PREV];

    const int tid = threadIdx.x;

    for (int j = tid; j < N_PREV; j += 256) {
        float x1 = floorf(boxes_prev[4*j+0] * 0.5f);
        float y1 = floorf(boxes_prev[4*j+1] * 0.5f);
        float x2 = floorf(boxes_prev[4*j+2] * 0.5f);
        float y2 = floorf(boxes_prev[4*j+3] * 0.5f);
        sbp[j]      = make_float4(x1, y1, x2, y2);
        sareap[j]   = (x2 - x1) * (y2 - y1);
        sidp[j]     = ids_prev[j];
        smatched[j] = 0;
    }
    __syncthreads();

    if (tid < N_CUR) {
        const int i = tid;
        float bx1 = floorf(boxes[4*i+0] * 0.5f);
        float by1 = floorf(boxes[4*i+1] * 0.5f);
        float bx2 = floorf(boxes[4*i+2] * 0.5f);
        float by2 = floorf(boxes[4*i+3] * 0.5f);
        float area = (bx2 - bx1) * (by2 - by1);
        const int myid = ids[i];

        int   midx = 0;            // argmax over all-false eq -> 0 (jnp semantics)
        bool  has_match = false;
        float iou_m = 0.0f;        // iou[i][midx]
        float iou0  = 0.0f;        // iou[i][0] fallback when no id match
        float best  = -INFINITY;   // max over iou_excl
        int   best_idx = 0;

        for (int j = 0; j < N_PREV; ++j) {
            float4 p = sbp[j];
            float ix1 = fmaxf(bx1, p.x);
            float iy1 = fmaxf(by1, p.y);
            float ix2 = fminf(bx2, p.z);
            float iy2 = fminf(by2, p.w);
            float inter = fmaxf(ix2 - ix1, 0.0f) * fmaxf(iy2 - iy1, 0.0f);
            float iou   = inter / (area + sareap[j] - inter);
            bool  eq    = (myid == sidp[j]);
            if (j == 0) iou0 = iou;
            if (eq && !has_match) { has_match = true; midx = j; iou_m = iou; }
            float cand = eq ? -1.0f : iou;       // iou_excl
            if (cand > best) { best = cand; best_idx = j; }  // strict > == first-index argmax
        }
        if (!has_match) iou_m = iou0;            // midx == 0 path

        const float fl   = flags[i];
        const bool flag1 = (fl == 1.0f);
        const bool has_best = (best > 0.0f);
        const float best_iou = fmaxf(best, 0.0f);
        const float ig1 = 1.0f - best_iou;
        const float ig0 = 1.0f - iou_m;
        const float sc  = scores[i];

        const float val_cur = flag1 ? (ig1 * sc) : (ig0 * sc * (1.0f - fl));

        const float sp1 = scores_prev[best_idx], fp1 = flags_prev[best_idx];
        const float v1  = ig1 * ((fp1 == 1.0f) ? sp1 : sp1 * (1.0f - fp1));
        const float sp0 = scores_prev[midx],     fp0 = flags_prev[midx];
        const float v0  = ig0 * ((fp0 == 1.0f) ? sp0 : sp0 * (1.0f - fl)); // (1 - current flag), per source

        const int   prev_j      = flag1 ? best_idx : midx;
        const float prev_v      = flag1 ? v1 : v0;
        const bool  prev_active = flag1 ? has_best : has_match;

        // current rect (always active)
        rbox[i] = make_float4(bx1, by1, bx2, by2);
        rval[i] = val_cur;

        // associated prev rect
        rbox[N_CUR + i] = prev_active ? sbp[prev_j] : make_float4(0,0,0,0);
        rval[N_CUR + i] = prev_active ? prev_v : 0.0f;

        if (prev_active) smatched[prev_j] = 1;   // all writers write 1; race benign
    }
    __syncthreads();

    // leftover (unmatched) prev rects
    for (int j = tid; j < N_PREV; j += 256) {
        bool act = (smatched[j] == 0);
        float sp = scores_prev[j], fp = flags_prev[j];
        float v  = (fp == 1.0f) ? sp : sp * (1.0f - fp);
        rbox[2*N_CUR + j] = act ? sbp[j] : make_float4(0,0,0,0);
        rval[2*N_CUR + j] = act ? v : 0.0f;
    }
}

// ---------------------------------------------------------------------------
// Kernel 2: tile-culled max paint at subsampled res, fused 2x nearest upsample.
// Block = 32x8 threads, one subsampled pixel per thread, writes a 2x2 block
// of the full-res output as two float2 stores (coalesced, 8B aligned).
// ---------------------------------------------------------------------------
__global__ __launch_bounds__(256) void paint_mask(
    const float4* __restrict__ rbox,
    const float*  __restrict__ rval,
    float* __restrict__ out)                 // [2160*3840]
{
    __shared__ float4 sbox[K_RECT];
    __shared__ float  sval[K_RECT];
    __shared__ int    scnt;

    const int tx  = threadIdx.x;             // 0..31
    const int ty  = threadIdx.y;             // 0..7
    const int tid = ty * TILE_W + tx;

    const int tileX0 = blockIdx.x * TILE_W;  // subsampled coords
    const int tileY0 = blockIdx.y * TILE_H;

    if (tid == 0) scnt = 0;
    __syncthreads();

    // cull + compact rects intersecting this tile
    for (int i = tid; i < K_RECT; i += 256) {
        float4 r = rbox[i];
        if (r.x < (float)(tileX0 + TILE_W) && r.z > (float)tileX0 &&
            r.y < (float)(tileY0 + TILE_H) && r.w > (float)tileY0 &&
            r.z > r.x) {
            int k = atomicAdd(&scnt, 1);
            sbox[k] = r;
            sval[k] = rval[i];
        }
    }
    __syncthreads();

    const int   sx = tileX0 + tx;
    const int   sy = tileY0 + ty;
    const float fx = (float)sx;
    const float fy = (float)sy;

    float m = 0.0f;
    const int cnt = scnt;
    for (int k = 0; k < cnt; ++k) {
        float4 r = sbox[k];
        bool inside = (fy >= r.y) & (fy < r.w) & (fx >= r.x) & (fx < r.z);
        m = inside ? fmaxf(m, sval[k]) : m;
    }

    // fused nearest-neighbor 2x upsample
    const int X = 2 * sx;
    const int Y = 2 * sy;
    float2 v2 = make_float2(m, m);
    *(float2*)(out + (size_t)Y       * W_FULL + X) = v2;
    *(float2*)(out + (size_t)(Y + 1) * W_FULL + X) = v2;
}

extern "C" void kernel_launch(void* const* d_in, const int* in_sizes, int n_in,
                              void* d_out, int out_size, void* d_ws, size_t ws_size,
                              hipStream_t stream) {
    // input order: inputs, boxes, scores, flags, boxes_prev, scores_prev,
    //              flags_prev, ids, ids_prev
    const float* boxes       = (const float*)d_in[1];
    const float* scores      = (const float*)d_in[2];
    const float* flags       = (const float*)d_in[3];
    const float* boxes_prev  = (const float*)d_in[4];
    const float* scores_prev = (const float*)d_in[5];
    const float* flags_prev  = (const float*)d_in[6];
    const int*   ids         = (const int*)d_in[7];
    const int*   ids_prev    = (const int*)d_in[8];
    float* out = (float*)d_out;

    float4* rbox = (float4*)d_ws;
    float*  rval = (float*)((char*)d_ws + K_RECT * sizeof(float4));

    prep_rects<<<1, 256, 0, stream>>>(boxes, scores, flags,
                                      boxes_prev, scores_prev, flags_prev,
                                      ids, ids_prev, rbox, rval);

    dim3 grid(WS / TILE_W, HS / TILE_H);   // 60 x 135, exact
    dim3 block(TILE_W, TILE_H);
    paint_mask<<<grid, block, 0, stream>>>(rbox, rval, out);
}

// Round 2
// 172.990 us; speedup vs baseline: 1.0069x; 1.0069x over previous
//
#include <hip/hip_runtime.h>
#include <math.h>

#define N_CUR 128
#define N_PREV 160
#define K_RECT (N_CUR + N_CUR + N_PREV)   // 416 rectangles
#define HS 1080                            // subsampled height
#define WS 1920                            // subsampled width
#define W_FULL 3840
#define TILE_W 64                          // subpixels per tile (x)
#define TILE_H 8                           // subpixels per tile (y)

// ---------------------------------------------------------------------------
// Kernel 1: matching logic -> rectangle list (box as float4 [x1,y1,x2,y2), val)
// Inactive rects are emitted as empty boxes (all zero) so the painter's
// geometric cull rejects them (r.z=0 can never exceed tileX0>=0).
// ---------------------------------------------------------------------------
__global__ __launch_bounds__(256) void prep_rects(
    const float* __restrict__ boxes,        // [N,4]
    const float* __restrict__ scores,       // [N]
    const float* __restrict__ flags,        // [N]
    const float* __restrict__ boxes_prev,   // [M,4]
    const float* __restrict__ scores_prev,  // [M]
    const float* __restrict__ flags_prev,   // [M]
    const int*   __restrict__ ids,          // [N]
    const int*   __restrict__ ids_prev,     // [M]
    float4* __restrict__ rbox,              // [K_RECT]
    float*  __restrict__ rval)              // [K_RECT]
{
    __shared__ float4 sbp[N_PREV];      // floored/2 prev boxes
    __shared__ float  sareap[N_PREV];
    __shared__ int    sidp[N_PREV];
    __shared__ int    smatched[N_PREV];

    const int tid = threadIdx.x;

    for (int j = tid; j < N_PREV; j += 256) {
        float x1 = floorf(boxes_prev[4*j+0] * 0.5f);
        float y1 = floorf(boxes_prev[4*j+1] * 0.5f);
        float x2 = floorf(boxes_prev[4*j+2] * 0.5f);
        float y2 = floorf(boxes_prev[4*j+3] * 0.5f);
        sbp[j]      = make_float4(x1, y1, x2, y2);
        sareap[j]   = (x2 - x1) * (y2 - y1);
        sidp[j]     = ids_prev[j];
        smatched[j] = 0;
    }
    __syncthreads();

    if (tid < N_CUR) {
        const int i = tid;
        float bx1 = floorf(boxes[4*i+0] * 0.5f);
        float by1 = floorf(boxes[4*i+1] * 0.5f);
        float bx2 = floorf(boxes[4*i+2] * 0.5f);
        float by2 = floorf(boxes[4*i+3] * 0.5f);
        float area = (bx2 - bx1) * (by2 - by1);
        const int myid = ids[i];

        int   midx = 0;            // argmax over all-false eq -> 0 (jnp semantics)
        bool  has_match = false;
        float iou_m = 0.0f;        // iou[i][midx]
        float iou0  = 0.0f;        // iou[i][0] fallback when no id match
        float best  = -INFINITY;   // max over iou_excl
        int   best_idx = 0;

        for (int j = 0; j < N_PREV; ++j) {
            float4 p = sbp[j];
            float ix1 = fmaxf(bx1, p.x);
            float iy1 = fmaxf(by1, p.y);
            float ix2 = fminf(bx2, p.z);
            float iy2 = fminf(by2, p.w);
            float inter = fmaxf(ix2 - ix1, 0.0f) * fmaxf(iy2 - iy1, 0.0f);
            float iou   = inter / (area + sareap[j] - inter);
            bool  eq    = (myid == sidp[j]);
            if (j == 0) iou0 = iou;
            if (eq && !has_match) { has_match = true; midx = j; iou_m = iou; }
            float cand = eq ? -1.0f : iou;       // iou_excl
            if (cand > best) { best = cand; best_idx = j; }  // strict > == first-index argmax
        }
        if (!has_match) iou_m = iou0;            // midx == 0 path

        const float fl   = flags[i];
        const bool flag1 = (fl == 1.0f);
        const bool has_best = (best > 0.0f);
        const float best_iou = fmaxf(best, 0.0f);
        const float ig1 = 1.0f - best_iou;
        const float ig0 = 1.0f - iou_m;
        const float sc  = scores[i];

        const float val_cur = flag1 ? (ig1 * sc) : (ig0 * sc * (1.0f - fl));

        const float sp1 = scores_prev[best_idx], fp1 = flags_prev[best_idx];
        const float v1  = ig1 * ((fp1 == 1.0f) ? sp1 : sp1 * (1.0f - fp1));
        const float sp0 = scores_prev[midx],     fp0 = flags_prev[midx];
        const float v0  = ig0 * ((fp0 == 1.0f) ? sp0 : sp0 * (1.0f - fl)); // (1 - current flag), per source

        const int   prev_j      = flag1 ? best_idx : midx;
        const float prev_v      = flag1 ? v1 : v0;
        const bool  prev_active = flag1 ? has_best : has_match;

        // current rect (always active)
        rbox[i] = make_float4(bx1, by1, bx2, by2);
        rval[i] = val_cur;

        // associated prev rect
        rbox[N_CUR + i] = prev_active ? sbp[prev_j] : make_float4(0,0,0,0);
        rval[N_CUR + i] = prev_active ? prev_v : 0.0f;

        if (prev_active) smatched[prev_j] = 1;   // all writers write 1; race benign
    }
    __syncthreads();

    // leftover (unmatched) prev rects
    for (int j = tid; j < N_PREV; j += 256) {
        bool act = (smatched[j] == 0);
        float sp = scores_prev[j], fp = flags_prev[j];
        float v  = (fp == 1.0f) ? sp : sp * (1.0f - fp);
        rbox[2*N_CUR + j] = act ? sbp[j] : make_float4(0,0,0,0);
        rval[2*N_CUR + j] = act ? v : 0.0f;
    }
}

// ---------------------------------------------------------------------------
// Kernel 2: tile-culled max paint at subsampled res, fused 2x nearest upsample.
// Block = 32x8 threads; each thread owns TWO adjacent subsampled pixels
// (sx0, sx0+1) in one row -> its upsampled output is a 4-wide x 2-tall block
// written as two coalesced float4 (16B) stores.
// ---------------------------------------------------------------------------
__global__ __launch_bounds__(256) void paint_mask(
    const float4* __restrict__ rbox,
    const float*  __restrict__ rval,
    float* __restrict__ out)                 // [2160*3840]
{
    __shared__ float4 sbox[K_RECT];
    __shared__ float  sval[K_RECT];
    __shared__ int    scnt;

    const int tx  = threadIdx.x;             // 0..31
    const int ty  = threadIdx.y;             // 0..7
    const int tid = ty * 32 + tx;

    const int tileX0 = blockIdx.x * TILE_W;  // subsampled coords
    const int tileY0 = blockIdx.y * TILE_H;

    if (tid == 0) scnt = 0;
    __syncthreads();

    // cull + compact rects intersecting this tile (empty boxes auto-fail)
    for (int i = tid; i < K_RECT; i += 256) {
        float4 r = rbox[i];
        if (r.x < (float)(tileX0 + TILE_W) && r.z > (float)tileX0 &&
            r.y < (float)(tileY0 + TILE_H) && r.w > (float)tileY0) {
            int k = atomicAdd(&scnt, 1);
            sbox[k] = r;
            sval[k] = rval[i];
        }
    }
    __syncthreads();

    const int   sx0 = tileX0 + 2 * tx;       // this thread's two subpixels: sx0, sx0+1
    const int   sy  = tileY0 + ty;
    const float fx0 = (float)sx0;
    const float fx1 = (float)(sx0 + 1);
    const float fy  = (float)sy;

    float m0 = 0.0f, m1 = 0.0f;
    const int cnt = scnt;
    for (int k = 0; k < cnt; ++k) {
        float4 r = sbox[k];
        float  v = sval[k];
        bool iny = (fy >= r.y) & (fy < r.w);
        bool in0 = iny & (fx0 >= r.x) & (fx0 < r.z);
        bool in1 = iny & (fx1 >= r.x) & (fx1 < r.z);
        m0 = in0 ? fmaxf(m0, v) : m0;
        m1 = in1 ? fmaxf(m1, v) : m1;
    }

    // fused nearest-neighbor 2x upsample: full-res cols 2*sx0 .. 2*sx0+3
    const int X = 2 * sx0;                   // divisible by 4 -> 16B aligned
    const int Y = 2 * sy;
    float4 v4 = make_float4(m0, m0, m1, m1);
    *(float4*)(out + (size_t)Y       * W_FULL + X) = v4;
    *(float4*)(out + (size_t)(Y + 1) * W_FULL + X) = v4;
}

extern "C" void kernel_launch(void* const* d_in, const int* in_sizes, int n_in,
                              void* d_out, int out_size, void* d_ws, size_t ws_size,
                              hipStream_t stream) {
    // input order: inputs, boxes, scores, flags, boxes_prev, scores_prev,
    //              flags_prev, ids, ids_prev
    const float* boxes       = (const float*)d_in[1];
    const float* scores      = (const float*)d_in[2];
    const float* flags       = (const float*)d_in[3];
    const float* boxes_prev  = (const float*)d_in[4];
    const float* scores_prev = (const float*)d_in[5];
    const float* flags_prev  = (const float*)d_in[6];
    const int*   ids         = (const int*)d_in[7];
    const int*   ids_prev    = (const int*)d_in[8];
    float* out = (float*)d_out;

    float4* rbox = (float4*)d_ws;
    float*  rval = (float*)((char*)d_ws + K_RECT * sizeof(float4));

    prep_rects<<<1, 256, 0, stream>>>(boxes, scores, flags,
                                      boxes_prev, scores_prev, flags_prev,
                                      ids, ids_prev, rbox, rval);

    dim3 grid(WS / TILE_W, HS / TILE_H);   // 30 x 135, exact
    dim3 block(32, TILE_H);
    paint_mask<<<grid, block, 0, stream>>>(rbox, rval, out);
}